// Round 7
// baseline (223.479 us; speedup 1.0000x reference)
//
#include <hip/hip_runtime.h>
#include <math.h>

#define NT 32768
#define DIM 2048
#define NE 64
#define RSCALE 2.5f
#define REPS 1e-20f
#define KC 32
#define NCH (DIM / KC)
#define TOK 64

typedef __attribute__((ext_vector_type(8))) short short8x;
typedef __attribute__((ext_vector_type(4))) float f32x4;
typedef __attribute__((ext_vector_type(4))) unsigned int uint4x;

// W bf16 limb planes, fragment-shaped: WLf[limb][chunk][expert-tile][lane] = 16 B
// (lane l: expert = et*16 + (l&15), k-octet = l>>4). 768 KB, L2-resident.
__device__ short8x WLf[3][NCH][4][64];

// pack hi16 of two fp32 into one dword (low half = even element)
#define PACKHI(odd, even) __builtin_amdgcn_perm((odd), (even), 0x07060302u)

__device__ __forceinline__ void decomp4(f32x4 x, unsigned int o[6]) {
    unsigned int u0 = __float_as_uint(x.x), u1 = __float_as_uint(x.y);
    unsigned int u2 = __float_as_uint(x.z), u3 = __float_as_uint(x.w);
    o[0] = PACKHI(u1, u0); o[1] = PACKHI(u3, u2);
    float r0 = x.x - __uint_as_float(u0 & 0xffff0000u);
    float r1 = x.y - __uint_as_float(u1 & 0xffff0000u);
    float r2 = x.z - __uint_as_float(u2 & 0xffff0000u);
    float r3 = x.w - __uint_as_float(u3 & 0xffff0000u);
    unsigned int v0 = __float_as_uint(r0), v1 = __float_as_uint(r1);
    unsigned int v2 = __float_as_uint(r2), v3 = __float_as_uint(r3);
    o[2] = PACKHI(v1, v0); o[3] = PACKHI(v3, v2);
    float s0 = r0 - __uint_as_float(v0 & 0xffff0000u);
    float s1 = r1 - __uint_as_float(v1 & 0xffff0000u);
    float s2 = r2 - __uint_as_float(v2 & 0xffff0000u);
    float s3 = r3 - __uint_as_float(v3 & 0xffff0000u);
    o[4] = PACKHI(__float_as_uint(s1), __float_as_uint(s0));
    o[5] = PACKHI(__float_as_uint(s3), __float_as_uint(s2));
}

__device__ __forceinline__ void decomp8(f32x4 a, f32x4 b,
                                        short8x* f0, short8x* f1, short8x* f2) {
    unsigned int oa[6], ob[6];
    decomp4(a, oa); decomp4(b, ob);
    uint4x t0 = {oa[0], oa[1], ob[0], ob[1]};
    uint4x t1 = {oa[2], oa[3], ob[2], ob[3]};
    uint4x t2 = {oa[4], oa[5], ob[4], ob[5]};
    *f0 = __builtin_bit_cast(short8x, t0);
    *f1 = __builtin_bit_cast(short8x, t1);
    *f2 = __builtin_bit_cast(short8x, t2);
}

// pre-pass: decompose W into fragment-shaped limb planes. 64 blocks x 256.
__global__ void decomp_w_kernel(const float* __restrict__ W) {
    const int ch = blockIdx.x;
    const int et = threadIdx.x >> 6;
    const int l  = threadIdx.x & 63;
    const float* src = W + (size_t)(et * 16 + (l & 15)) * DIM + ch * KC + (l >> 4) * 8;
    f32x4 lo = *(const f32x4*)src;
    f32x4 hi = *(const f32x4*)(src + 4);
    short8x f0, f1, f2;
    decomp8(lo, hi, &f0, &f1, &f2);
    WLf[0][ch][et][l] = f0;
    WLf[1][ch][et][l] = f1;
    WLf[2][ch][et][l] = f2;
}

// 512 blocks x 256 threads (4 waves). Wave w = token-tile tb + w*16 (16 tokens) x all
// 64 experts x full K: barrier-free main loop, A direct from global (one f32x8 per lane
// per chunk = the whole A-fragment), B fragments direct from WLf. MFMA order, chunk
// order, and fp64 drain points identical to the previously passing kernel.
__global__ __launch_bounds__(256, 2) void router_kernel(
    const float* __restrict__ H,
    const float* __restrict__ W,
    const float* __restrict__ B,
    float* __restrict__ out)
{
    __shared__ float scf[TOK * 65];
    __shared__ float bsf[NE];

    const int tid  = threadIdx.x;
    const int lane = tid & 63;
    const int w    = __builtin_amdgcn_readfirstlane(tid >> 6);
    const int l15  = lane & 15, g = lane >> 4;
    const size_t tb = (size_t)blockIdx.x * TOK;

    if (tid < NE) bsf[tid] = B[tid];

    // lane l loads H[token = tb + w*16 + (l&15)][ch*32 + (l>>4)*8 .. +7]
    const float* hsrc = H + (tb + (size_t)(w * 16 + l15)) * DIM + g * 8;

    f32x4 Cm[4], Cc[4];
    double md[4][4];
    #pragma unroll
    for (int et = 0; et < 4; ++et) {
        Cm[et] = (f32x4)0.0f; Cc[et] = (f32x4)0.0f;
        #pragma unroll
        for (int r = 0; r < 4; ++r) md[et][r] = 0.0;
    }

    f32x4 aLo = *(const f32x4*)hsrc;
    f32x4 aHi = *(const f32x4*)(hsrc + 4);

    #pragma unroll 2
    for (int ch = 0; ch < NCH; ++ch) {
        // prefetch next chunk's A (clamped on last iter; value unused)
        const int chn = (ch + 1 < NCH) ? (ch + 1) : ch;
        const float* np = hsrc + chn * KC;
        f32x4 nLo = *(const f32x4*)np;
        f32x4 nHi = *(const f32x4*)(np + 4);

        short8x a0, a1, a2;
        decomp8(aLo, aHi, &a0, &a1, &a2);

        #pragma unroll
        for (int et = 0; et < 4; ++et) {
            short8x b0 = WLf[0][ch][et][lane];
            short8x b1 = WLf[1][ch][et][lane];
            short8x b2 = WLf[2][ch][et][lane];
            Cm[et] = __builtin_amdgcn_mfma_f32_16x16x32_bf16(a0, b0, Cm[et], 0, 0, 0);
            Cc[et] = __builtin_amdgcn_mfma_f32_16x16x32_bf16(a1, b0, Cc[et], 0, 0, 0);
            Cc[et] = __builtin_amdgcn_mfma_f32_16x16x32_bf16(a2, b0, Cc[et], 0, 0, 0);
            Cc[et] = __builtin_amdgcn_mfma_f32_16x16x32_bf16(a0, b1, Cc[et], 0, 0, 0);
            Cc[et] = __builtin_amdgcn_mfma_f32_16x16x32_bf16(a1, b1, Cc[et], 0, 0, 0);
            Cc[et] = __builtin_amdgcn_mfma_f32_16x16x32_bf16(a0, b2, Cc[et], 0, 0, 0);
        }

        // fp64 master drain every 8 chunks (K=256) -- same points as passing kernel
        if ((ch & 7) == 7) {
            #pragma unroll
            for (int et = 0; et < 4; ++et) {
                #pragma unroll
                for (int r = 0; r < 4; ++r)
                    md[et][r] += (double)Cm[et][r] + (double)Cc[et][r];
                Cm[et] = (f32x4)0.0f; Cc[et] = (f32x4)0.0f;
            }
        }
        aLo = nLo; aHi = nHi;
    }

    // sigmoid scores -> LDS (C layout: token = w*16 + g*4 + r, expert = et*16 + l15)
    #pragma unroll
    for (int et = 0; et < 4; ++et)
        #pragma unroll
        for (int r = 0; r < 4; ++r) {
            float logit = (float)md[et][r];
            float s = 1.0f / (1.0f + expf(-logit));
            int t = w * 16 + g * 4 + r;
            int e = et * 16 + l15;
            scf[t * 65 + e] = s;
        }
    __syncthreads();

    // grouped top-k, one token per active thread (64 tokens over 4 waves)
    if ((tid & 3) == 0) {
        const int t = tid >> 2;
        const float* sc = &scf[t * 65];
        float gs[8];
        #pragma unroll
        for (int gg = 0; gg < 8; ++gg) {
            float m1 = -1e30f, m2 = -1e30f;
            #pragma unroll
            for (int j = 0; j < 8; ++j) {
                float v = sc[gg * 8 + j] + bsf[gg * 8 + j];
                if (v > m1) { m2 = m1; m1 = v; }
                else if (v > m2) { m2 = v; }
            }
            gs[gg] = m1 + m2;
        }
        unsigned gmask = 0;
        for (int i = 0; i < 4; ++i) {
            float best = -1e30f; int bg = 0;
            for (int gg = 0; gg < 8; ++gg)
                if (!((gmask >> gg) & 1u) && gs[gg] > best) { best = gs[gg]; bg = gg; }
            gmask |= 1u << bg;
        }
        unsigned long long picked = 0ull;
        int   idxs[8];
        float wts[8];
        float wsum = 0.0f;
        for (int i = 0; i < 8; ++i) {
            float best = -1e30f; int bi = 0;
            for (int e = 0; e < 64; ++e) {
                if ((picked >> e) & 1ull) continue;
                float v = ((gmask >> (e >> 3)) & 1u) ? (sc[e] + bsf[e]) : 0.0f;
                if (v > best) { best = v; bi = e; }
            }
            picked |= 1ull << bi;
            idxs[i] = bi;
            wts[i] = sc[bi];
            wsum += sc[bi];
        }
        const float scale = RSCALE / (wsum + REPS);
        const size_t token = tb + t;
        #pragma unroll
        for (int i = 0; i < 8; ++i) {
            out[token * 8 + i] = (float)idxs[i];
            out[(size_t)NT * 8 + token * 8 + i] = wts[i] * scale;
        }
    }
}

extern "C" void kernel_launch(void* const* d_in, const int* in_sizes, int n_in,
                              void* d_out, int out_size, void* d_ws, size_t ws_size,
                              hipStream_t stream) {
    (void)in_sizes; (void)n_in; (void)out_size; (void)d_ws; (void)ws_size;
    const float* H = (const float*)d_in[0];
    const float* W = (const float*)d_in[1];
    const float* B = (const float*)d_in[2];
    float* out = (float*)d_out;
    decomp_w_kernel<<<dim3(NCH), dim3(256), 0, stream>>>(W);
    router_kernel<<<dim3(NT / TOK), dim3(256), 0, stream>>>(H, W, B, out);
}

// Round 8
// 140.405 us; speedup vs baseline: 1.5917x; 1.5917x over previous
//
#include <hip/hip_runtime.h>
#include <math.h>

#define NT 32768
#define DIM 2048
#define NE 64
#define RSCALE 2.5f
#define REPS 1e-20f
#define KC 32
#define NCH (DIM / KC)
#define TOK 64

// LDS arena (bytes):
//   HL[2][3][64 tok][4 slots x 16B]  : 0     .. 24575   (H bf16 limb planes, dbuf)
//   WL[2][3][64 exp][4 slots x 16B]  : 24576 .. 49151   (W bf16 limb planes, dbuf)
//   Bs[64] f32                       : 49152 .. 49407
//   Sc[64][65] f32                   : alias at 0 (epilogue only)
#define HL_BUF 12288
#define WL_OFF 24576
#define BS_OFF 49152
#define ARENA 49408

typedef __attribute__((ext_vector_type(8))) short short8x;
typedef __attribute__((ext_vector_type(4))) float f32x4;
typedef __attribute__((ext_vector_type(4))) unsigned int uint4x;

// pack hi16 of two fp32 into one dword (low half = even element)
#define PACKHI(odd, even) __builtin_amdgcn_perm((odd), (even), 0x07060302u)

__device__ __forceinline__ void decomp4(f32x4 x, unsigned int o[6]) {
    unsigned int u0 = __float_as_uint(x.x), u1 = __float_as_uint(x.y);
    unsigned int u2 = __float_as_uint(x.z), u3 = __float_as_uint(x.w);
    o[0] = PACKHI(u1, u0); o[1] = PACKHI(u3, u2);
    float r0 = x.x - __uint_as_float(u0 & 0xffff0000u);
    float r1 = x.y - __uint_as_float(u1 & 0xffff0000u);
    float r2 = x.z - __uint_as_float(u2 & 0xffff0000u);
    float r3 = x.w - __uint_as_float(u3 & 0xffff0000u);
    unsigned int v0 = __float_as_uint(r0), v1 = __float_as_uint(r1);
    unsigned int v2 = __float_as_uint(r2), v3 = __float_as_uint(r3);
    o[2] = PACKHI(v1, v0); o[3] = PACKHI(v3, v2);
    float s0 = r0 - __uint_as_float(v0 & 0xffff0000u);
    float s1 = r1 - __uint_as_float(v1 & 0xffff0000u);
    float s2 = r2 - __uint_as_float(v2 & 0xffff0000u);
    float s3 = r3 - __uint_as_float(v3 & 0xffff0000u);
    o[4] = PACKHI(__float_as_uint(s1), __float_as_uint(s0));
    o[5] = PACKHI(__float_as_uint(s3), __float_as_uint(s2));
}

__device__ __forceinline__ void decomp8(f32x4 a, f32x4 b,
                                        short8x* f0, short8x* f1, short8x* f2) {
    unsigned int oa[6], ob[6];
    decomp4(a, oa); decomp4(b, ob);
    uint4x t0 = {oa[0], oa[1], ob[0], ob[1]};
    uint4x t1 = {oa[2], oa[3], ob[2], ob[3]};
    uint4x t2 = {oa[4], oa[5], ob[4], ob[5]};
    *f0 = __builtin_bit_cast(short8x, t0);
    *f1 = __builtin_bit_cast(short8x, t1);
    *f2 = __builtin_bit_cast(short8x, t2);
}

// counted-vmcnt barrier (T4): commit LDS ops, sync, but leave global loads in flight.
// (plain __syncthreads() would emit s_waitcnt vmcnt(0) and defeat the reg prefetch)
#define BARRIER() do { \
    asm volatile("s_waitcnt lgkmcnt(0)" ::: "memory"); \
    __builtin_amdgcn_s_barrier(); \
    __builtin_amdgcn_sched_barrier(0); \
} while (0)

// issue chunk (KOFF) global loads into named reg slot
#define STAGE_ISSUE(SA, SB, KOFF) do { \
    SA = *(const f32x4*)(gsrc + (KOFF));     \
    SB = *(const f32x4*)(gsrc + (KOFF) + 4); \
} while (0)

// decompose staged regs and write limb planes of buffer PN
#define STAGE_WRITE(SA, SB, PN) do { \
    short8x f0_, f1_, f2_; \
    decomp8(SA, SB, &f0_, &f1_, &f2_); \
    *(short8x*)(arena + sbase + (PN) * HL_BUF + 0 * 4096 + soff) = f0_; \
    *(short8x*)(arena + sbase + (PN) * HL_BUF + 1 * 4096 + soff) = f1_; \
    *(short8x*)(arena + sbase + (PN) * HL_BUF + 2 * 4096 + soff) = f2_; \
} while (0)

// read A (1 token-tile) + B (2 expert-tiles) limb frags from buffer P, 12 MFMAs
#define COMPUTE(P) do { \
    const char* hb = arena + (P) * HL_BUF; \
    const char* wb = arena + WL_OFF + (P) * HL_BUF; \
    short8x a0, a1, a2; \
    { const int t_ = tt * 16 + l15; \
      const int ro_ = t_ * 64 + ((g ^ ((t_ >> 1) & 3)) << 4); \
      a0 = *(const short8x*)(hb + 0 * 4096 + ro_); \
      a1 = *(const short8x*)(hb + 1 * 4096 + ro_); \
      a2 = *(const short8x*)(hb + 2 * 4096 + ro_); } \
    _Pragma("unroll") \
    for (int et = 0; et < 2; ++et) { \
        const int e_ = ep * 32 + et * 16 + l15; \
        const int ro_ = e_ * 64 + ((g ^ ((e_ >> 1) & 3)) << 4); \
        short8x b0 = *(const short8x*)(wb + 0 * 4096 + ro_); \
        short8x b1 = *(const short8x*)(wb + 1 * 4096 + ro_); \
        short8x b2 = *(const short8x*)(wb + 2 * 4096 + ro_); \
        Cm[et] = __builtin_amdgcn_mfma_f32_16x16x32_bf16(a0, b0, Cm[et], 0, 0, 0); \
        Cc[et] = __builtin_amdgcn_mfma_f32_16x16x32_bf16(a1, b0, Cc[et], 0, 0, 0); \
        Cc[et] = __builtin_amdgcn_mfma_f32_16x16x32_bf16(a2, b0, Cc[et], 0, 0, 0); \
        Cc[et] = __builtin_amdgcn_mfma_f32_16x16x32_bf16(a0, b1, Cc[et], 0, 0, 0); \
        Cc[et] = __builtin_amdgcn_mfma_f32_16x16x32_bf16(a1, b1, Cc[et], 0, 0, 0); \
        Cc[et] = __builtin_amdgcn_mfma_f32_16x16x32_bf16(a0, b2, Cc[et], 0, 0, 0); \
    } \
} while (0)

#define DRAIN do { \
    _Pragma("unroll") \
    for (int et = 0; et < 2; ++et) { \
        _Pragma("unroll") \
        for (int r = 0; r < 4; ++r) \
            md[et][r] += (double)Cm[et][r] + (double)Cc[et][r]; \
        Cm[et] = (f32x4)0.0f; Cc[et] = (f32x4)0.0f; \
    } \
} while (0)

// 512 blocks x 512 threads (8 waves). Block = 64 tok x 64 exp; wave w: token-tile w&3,
// expert-pair w>>2. H,W decomposed ONCE into LDS bf16 limb planes (tid<256 stages H,
// tid>=256 stages W); depth-2 global reg prefetch; counted-vmcnt barrier per K-chunk.
__global__ __launch_bounds__(512, 4) void router_kernel(
    const float* __restrict__ H,
    const float* __restrict__ W,
    const float* __restrict__ B,
    float* __restrict__ out)
{
    __shared__ __align__(16) char arena[ARENA];
    float* bsf = (float*)(arena + BS_OFF);
    float* scf = (float*)(arena);

    const int tid  = threadIdx.x;
    const int lane = tid & 63;
    const int w    = __builtin_amdgcn_readfirstlane(tid >> 6);
    const int l15  = lane & 15, g = lane >> 4;
    const size_t tb = (size_t)blockIdx.x * TOK;

    if (tid < NE) bsf[tid] = B[tid];

    // staging role: row (token or expert) = (tid&255)>>2, k-octet = tid&3
    const int si   = tid & 255;
    const int srow = si >> 2;
    const int sq   = si & 3;
    const bool isH = tid < 256;
    const float* gsrc = isH ? (H + (tb + (size_t)srow) * DIM + sq * 8)
                            : (W + (size_t)srow * DIM + sq * 8);
    const int sbase = isH ? 0 : WL_OFF;
    const int soff  = srow * 64 + ((sq ^ ((srow >> 1) & 3)) << 4);

    // compute role
    const int tt = w & 3, ep = w >> 2;

    f32x4 Cm[2], Cc[2];
    double md[2][4];
    #pragma unroll
    for (int et = 0; et < 2; ++et) {
        Cm[et] = (f32x4)0.0f; Cc[et] = (f32x4)0.0f;
        #pragma unroll
        for (int r = 0; r < 4; ++r) md[et][r] = 0.0;
    }

    f32x4 sA0, sA1, sB0, sB1;

    // prologue: chunk0 -> buf0; issue chunk1 into slot B
    STAGE_ISSUE(sA0, sA1, 0);
    STAGE_WRITE(sA0, sA1, 0);
    STAGE_ISSUE(sB0, sB1, KC);
    BARRIER();

    for (int chb = 0; chb < NCH; chb += 2) {
        // even chunk chb: read buf0; write chb+1 (slot B) -> buf1; issue chb+2 -> slot A
        if (chb + 2 < NCH) STAGE_ISSUE(sA0, sA1, (chb + 2) * KC);
        COMPUTE(0);
        STAGE_WRITE(sB0, sB1, 1);
        BARRIER();

        // odd chunk chb+1: read buf1; write chb+2 (slot A) -> buf0; issue chb+3 -> slot B
        if (chb + 3 < NCH) STAGE_ISSUE(sB0, sB1, (chb + 3) * KC);
        COMPUTE(1);
        if (chb + 2 < NCH) STAGE_WRITE(sA0, sA1, 0);
        if (((chb + 1) & 7) == 7) DRAIN;
        BARRIER();
    }

    // sigmoid scores -> Sc (aliases dead limb planes; all reads done at last barrier)
    #pragma unroll
    for (int et = 0; et < 2; ++et)
        #pragma unroll
        for (int r = 0; r < 4; ++r) {
            float logit = (float)md[et][r];
            float s = 1.0f / (1.0f + expf(-logit));
            int t = tt * 16 + g * 4 + r;
            int e = ep * 32 + et * 16 + l15;
            scf[t * 65 + e] = s;
        }
    __syncthreads();

    // grouped top-k, one token per active thread (64 tokens over 8 waves)
    if ((tid & 7) == 0) {
        const int t = tid >> 3;
        const float* sc = &scf[t * 65];
        float gs[8];
        #pragma unroll
        for (int gg = 0; gg < 8; ++gg) {
            float m1 = -1e30f, m2 = -1e30f;
            #pragma unroll
            for (int j = 0; j < 8; ++j) {
                float v = sc[gg * 8 + j] + bsf[gg * 8 + j];
                if (v > m1) { m2 = m1; m1 = v; }
                else if (v > m2) { m2 = v; }
            }
            gs[gg] = m1 + m2;
        }
        unsigned gmask = 0;
        for (int i = 0; i < 4; ++i) {
            float best = -1e30f; int bg = 0;
            for (int gg = 0; gg < 8; ++gg)
                if (!((gmask >> gg) & 1u) && gs[gg] > best) { best = gs[gg]; bg = gg; }
            gmask |= 1u << bg;
        }
        unsigned long long picked = 0ull;
        int   idxs[8];
        float wts[8];
        float wsum = 0.0f;
        for (int i = 0; i < 8; ++i) {
            float best = -1e30f; int bi = 0;
            for (int e = 0; e < 64; ++e) {
                if ((picked >> e) & 1ull) continue;
                float v = ((gmask >> (e >> 3)) & 1u) ? (sc[e] + bsf[e]) : 0.0f;
                if (v > best) { best = v; bi = e; }
            }
            picked |= 1ull << bi;
            idxs[i] = bi;
            wts[i] = sc[bi];
            wsum += sc[bi];
        }
        const float scale = RSCALE / (wsum + REPS);
        const size_t token = tb + t;
        #pragma unroll
        for (int i = 0; i < 8; ++i) {
            out[token * 8 + i] = (float)idxs[i];
            out[(size_t)NT * 8 + token * 8 + i] = wts[i] * scale;
        }
    }
}

extern "C" void kernel_launch(void* const* d_in, const int* in_sizes, int n_in,
                              void* d_out, int out_size, void* d_ws, size_t ws_size,
                              hipStream_t stream) {
    (void)in_sizes; (void)n_in; (void)out_size; (void)d_ws; (void)ws_size;
    const float* H = (const float*)d_in[0];
    const float* W = (const float*)d_in[1];
    const float* B = (const float*)d_in[2];
    float* out = (float*)d_out;
    router_kernel<<<dim3(NT / TOK), dim3(512), 0, stream>>>(H, W, B, out);
}

// Round 9
// 131.718 us; speedup vs baseline: 1.6967x; 1.0660x over previous
//
#include <hip/hip_runtime.h>
#include <math.h>

#define NT 32768
#define DIM 2048
#define NE 64
#define RSCALE 2.5f
#define REPS 1e-20f
#define KC 32
#define NCH (DIM / KC)
#define TOK 64

// LDS arena (bytes):
//   HL[2][3][64 tok][4 slots x 16B]  : 0     .. 24575   (H bf16 limb planes, dbuf)
//   WL[2][3][64 exp][4 slots x 16B]  : 24576 .. 49151   (W bf16 limb planes, dbuf)
//   Bs[64] f32                       : 49152 .. 49407
//   Sc[64][65] f32                   : alias at 0 (epilogue only)
#define HL_BUF 12288
#define WL_OFF 24576
#define BS_OFF 49152
#define ARENA 49408

typedef __attribute__((ext_vector_type(8))) short short8x;
typedef __attribute__((ext_vector_type(4))) float f32x4;
typedef __attribute__((ext_vector_type(4))) unsigned int uint4x;

// pack hi16 of two fp32 into one dword (low half = even element)
#define PACKHI(odd, even) __builtin_amdgcn_perm((odd), (even), 0x07060302u)

__device__ __forceinline__ void decomp4(f32x4 x, unsigned int o[6]) {
    unsigned int u0 = __float_as_uint(x.x), u1 = __float_as_uint(x.y);
    unsigned int u2 = __float_as_uint(x.z), u3 = __float_as_uint(x.w);
    o[0] = PACKHI(u1, u0); o[1] = PACKHI(u3, u2);
    float r0 = x.x - __uint_as_float(u0 & 0xffff0000u);
    float r1 = x.y - __uint_as_float(u1 & 0xffff0000u);
    float r2 = x.z - __uint_as_float(u2 & 0xffff0000u);
    float r3 = x.w - __uint_as_float(u3 & 0xffff0000u);
    unsigned int v0 = __float_as_uint(r0), v1 = __float_as_uint(r1);
    unsigned int v2 = __float_as_uint(r2), v3 = __float_as_uint(r3);
    o[2] = PACKHI(v1, v0); o[3] = PACKHI(v3, v2);
    float s0 = r0 - __uint_as_float(v0 & 0xffff0000u);
    float s1 = r1 - __uint_as_float(v1 & 0xffff0000u);
    float s2 = r2 - __uint_as_float(v2 & 0xffff0000u);
    float s3 = r3 - __uint_as_float(v3 & 0xffff0000u);
    o[4] = PACKHI(__float_as_uint(s1), __float_as_uint(s0));
    o[5] = PACKHI(__float_as_uint(s3), __float_as_uint(s2));
}

__device__ __forceinline__ void decomp8(f32x4 a, f32x4 b,
                                        short8x* f0, short8x* f1, short8x* f2) {
    unsigned int oa[6], ob[6];
    decomp4(a, oa); decomp4(b, ob);
    uint4x t0 = {oa[0], oa[1], ob[0], ob[1]};
    uint4x t1 = {oa[2], oa[3], ob[2], ob[3]};
    uint4x t2 = {oa[4], oa[5], ob[4], ob[5]};
    *f0 = __builtin_bit_cast(short8x, t0);
    *f1 = __builtin_bit_cast(short8x, t1);
    *f2 = __builtin_bit_cast(short8x, t2);
}

// counted-vmcnt barrier (T4): commit LDS ops, sync, leave global loads in flight.
#define BARRIER() do { \
    asm volatile("s_waitcnt lgkmcnt(0)" ::: "memory"); \
    __builtin_amdgcn_s_barrier(); \
    __builtin_amdgcn_sched_barrier(0); \
} while (0)

// issue chunk (KOFF) global loads (H octet + W octet) into named reg slot
#define STAGE_ISSUE(HA, HB, WA, WB, KOFF) do { \
    HA = *(const f32x4*)(hgsrc + (KOFF));     \
    HB = *(const f32x4*)(hgsrc + (KOFF) + 4); \
    WA = *(const f32x4*)(wgsrc + (KOFF));     \
    WB = *(const f32x4*)(wgsrc + (KOFF) + 4); \
} while (0)

// decompose staged regs and write H+W limb planes of buffer PN
#define STAGE_WRITE(HA, HB, WA, WB, PN) do { \
    short8x f0_, f1_, f2_; \
    decomp8(HA, HB, &f0_, &f1_, &f2_); \
    *(short8x*)(arena + (PN) * HL_BUF + 0 * 4096 + soff) = f0_; \
    *(short8x*)(arena + (PN) * HL_BUF + 1 * 4096 + soff) = f1_; \
    *(short8x*)(arena + (PN) * HL_BUF + 2 * 4096 + soff) = f2_; \
    decomp8(WA, WB, &f0_, &f1_, &f2_); \
    *(short8x*)(arena + WL_OFF + (PN) * HL_BUF + 0 * 4096 + soff) = f0_; \
    *(short8x*)(arena + WL_OFF + (PN) * HL_BUF + 1 * 4096 + soff) = f1_; \
    *(short8x*)(arena + WL_OFF + (PN) * HL_BUF + 2 * 4096 + soff) = f2_; \
} while (0)

// wave = 32 tok x 32 exp = 2x2 of 16x16 tiles; 12 b128 reads feed 24 MFMAs.
// Per-tile MFMA order identical to the previously passing kernel (bit-identical logits).
#define COMPUTE(P) do { \
    const char* hb = arena + (P) * HL_BUF; \
    const char* wb = arena + WL_OFF + (P) * HL_BUF; \
    short8x a0[2], a1[2], a2[2]; \
    _Pragma("unroll") \
    for (int tt = 0; tt < 2; ++tt) { \
        const int t_ = wr * 32 + tt * 16 + l15; \
        const int ro_ = t_ * 64 + ((g ^ ((t_ >> 1) & 3)) << 4); \
        a0[tt] = *(const short8x*)(hb + 0 * 4096 + ro_); \
        a1[tt] = *(const short8x*)(hb + 1 * 4096 + ro_); \
        a2[tt] = *(const short8x*)(hb + 2 * 4096 + ro_); \
    } \
    _Pragma("unroll") \
    for (int et = 0; et < 2; ++et) { \
        const int e_ = wc * 32 + et * 16 + l15; \
        const int ro_ = e_ * 64 + ((g ^ ((e_ >> 1) & 3)) << 4); \
        short8x b0 = *(const short8x*)(wb + 0 * 4096 + ro_); \
        short8x b1 = *(const short8x*)(wb + 1 * 4096 + ro_); \
        short8x b2 = *(const short8x*)(wb + 2 * 4096 + ro_); \
        _Pragma("unroll") \
        for (int tt = 0; tt < 2; ++tt) { \
            Cm[tt][et] = __builtin_amdgcn_mfma_f32_16x16x32_bf16(a0[tt], b0, Cm[tt][et], 0, 0, 0); \
            Cc[tt][et] = __builtin_amdgcn_mfma_f32_16x16x32_bf16(a1[tt], b0, Cc[tt][et], 0, 0, 0); \
            Cc[tt][et] = __builtin_amdgcn_mfma_f32_16x16x32_bf16(a2[tt], b0, Cc[tt][et], 0, 0, 0); \
            Cc[tt][et] = __builtin_amdgcn_mfma_f32_16x16x32_bf16(a0[tt], b1, Cc[tt][et], 0, 0, 0); \
            Cc[tt][et] = __builtin_amdgcn_mfma_f32_16x16x32_bf16(a1[tt], b1, Cc[tt][et], 0, 0, 0); \
            Cc[tt][et] = __builtin_amdgcn_mfma_f32_16x16x32_bf16(a0[tt], b2, Cc[tt][et], 0, 0, 0); \
        } \
    } \
} while (0)

#define DRAIN do { \
    _Pragma("unroll") \
    for (int tt = 0; tt < 2; ++tt) \
        _Pragma("unroll") \
        for (int et = 0; et < 2; ++et) { \
            _Pragma("unroll") \
            for (int r = 0; r < 4; ++r) \
                md[tt][et][r] += (double)Cm[tt][et][r] + (double)Cc[tt][et][r]; \
            Cm[tt][et] = (f32x4)0.0f; Cc[tt][et] = (f32x4)0.0f; \
        } \
} while (0)

// 512 blocks x 256 threads (4 waves). Block = 64 tok x 64 exp; wave w: token-half w&1,
// expert-half w>>1, each wave a 32x32 output (2x2 16x16 tiles, 24 MFMA/chunk).
// Each thread stages one H octet + one W octet per chunk (decompose once, share via LDS).
// Depth-2 global reg prefetch; counted-vmcnt barrier per K-chunk. 2 blocks/CU.
__global__ __launch_bounds__(256, 2) void router_kernel(
    const float* __restrict__ H,
    const float* __restrict__ W,
    const float* __restrict__ B,
    float* __restrict__ out)
{
    __shared__ __align__(16) char arena[ARENA];
    float* bsf = (float*)(arena + BS_OFF);
    float* scf = (float*)(arena);

    const int tid  = threadIdx.x;
    const int lane = tid & 63;
    const int w    = __builtin_amdgcn_readfirstlane(tid >> 6);
    const int l15  = lane & 15, g = lane >> 4;
    const size_t tb = (size_t)blockIdx.x * TOK;

    if (tid < NE) bsf[tid] = B[tid];

    // staging role: row = tid>>2 (0..63), k-octet = tid&3; thread stages H row AND W row
    const int srow = tid >> 2;
    const int sq   = tid & 3;
    const float* hgsrc = H + (tb + (size_t)srow) * DIM + sq * 8;
    const float* wgsrc = W + (size_t)srow * DIM + sq * 8;
    const int soff = srow * 64 + ((sq ^ ((srow >> 1) & 3)) << 4);

    // compute role: wave quadrant
    const int wr = w & 1, wc = w >> 1;

    f32x4 Cm[2][2], Cc[2][2];
    double md[2][2][4];
    #pragma unroll
    for (int tt = 0; tt < 2; ++tt)
        #pragma unroll
        for (int et = 0; et < 2; ++et) {
            Cm[tt][et] = (f32x4)0.0f; Cc[tt][et] = (f32x4)0.0f;
            #pragma unroll
            for (int r = 0; r < 4; ++r) md[tt][et][r] = 0.0;
        }

    f32x4 hA0, hA1, wA0, wA1, hB0, hB1, wB0, wB1;

    // prologue: chunk0 -> buf0; issue chunk1 into slot B
    STAGE_ISSUE(hA0, hA1, wA0, wA1, 0);
    STAGE_WRITE(hA0, hA1, wA0, wA1, 0);
    STAGE_ISSUE(hB0, hB1, wB0, wB1, KC);
    BARRIER();

    for (int chb = 0; chb < NCH; chb += 2) {
        // even chunk chb: read buf0; write chb+1 (slot B) -> buf1; issue chb+2 -> slot A
        if (chb + 2 < NCH) STAGE_ISSUE(hA0, hA1, wA0, wA1, (chb + 2) * KC);
        COMPUTE(0);
        STAGE_WRITE(hB0, hB1, wB0, wB1, 1);
        BARRIER();

        // odd chunk chb+1: read buf1; write chb+2 (slot A) -> buf0; issue chb+3 -> slot B
        if (chb + 3 < NCH) STAGE_ISSUE(hB0, hB1, wB0, wB1, (chb + 3) * KC);
        COMPUTE(1);
        if (chb + 2 < NCH) STAGE_WRITE(hA0, hA1, wA0, wA1, 0);
        if (((chb + 1) & 7) == 7) DRAIN;
        BARRIER();
    }

    // sigmoid scores -> Sc (aliases dead limb planes; all reads done at last barrier)
    #pragma unroll
    for (int tt = 0; tt < 2; ++tt)
        #pragma unroll
        for (int et = 0; et < 2; ++et)
            #pragma unroll
            for (int r = 0; r < 4; ++r) {
                float logit = (float)md[tt][et][r];
                float s = 1.0f / (1.0f + expf(-logit));
                int t = wr * 32 + tt * 16 + g * 4 + r;
                int e = wc * 32 + et * 16 + l15;
                scf[t * 65 + e] = s;
            }
    __syncthreads();

    // grouped top-k, one token per active thread (64 tokens over 4 waves)
    if ((tid & 3) == 0) {
        const int t = tid >> 2;
        const float* sc = &scf[t * 65];
        float gs[8];
        #pragma unroll
        for (int gg = 0; gg < 8; ++gg) {
            float m1 = -1e30f, m2 = -1e30f;
            #pragma unroll
            for (int j = 0; j < 8; ++j) {
                float v = sc[gg * 8 + j] + bsf[gg * 8 + j];
                if (v > m1) { m2 = m1; m1 = v; }
                else if (v > m2) { m2 = v; }
            }
            gs[gg] = m1 + m2;
        }
        unsigned gmask = 0;
        for (int i = 0; i < 4; ++i) {
            float best = -1e30f; int bg = 0;
            for (int gg = 0; gg < 8; ++gg)
                if (!((gmask >> gg) & 1u) && gs[gg] > best) { best = gs[gg]; bg = gg; }
            gmask |= 1u << bg;
        }
        unsigned long long picked = 0ull;
        int   idxs[8];
        float wts[8];
        float wsum = 0.0f;
        for (int i = 0; i < 8; ++i) {
            float best = -1e30f; int bi = 0;
            for (int e = 0; e < 64; ++e) {
                if ((picked >> e) & 1ull) continue;
                float v = ((gmask >> (e >> 3)) & 1u) ? (sc[e] + bsf[e]) : 0.0f;
                if (v > best) { best = v; bi = e; }
            }
            picked |= 1ull << bi;
            idxs[i] = bi;
            wts[i] = sc[bi];
            wsum += sc[bi];
        }
        const float scale = RSCALE / (wsum + REPS);
        const size_t token = tb + t;
        #pragma unroll
        for (int i = 0; i < 8; ++i) {
            out[token * 8 + i] = (float)idxs[i];
            out[(size_t)NT * 8 + token * 8 + i] = wts[i] * scale;
        }
    }
}

extern "C" void kernel_launch(void* const* d_in, const int* in_sizes, int n_in,
                              void* d_out, int out_size, void* d_ws, size_t ws_size,
                              hipStream_t stream) {
    (void)in_sizes; (void)n_in; (void)out_size; (void)d_ws; (void)ws_size;
    const float* H = (const float*)d_in[0];
    const float* W = (const float*)d_in[1];
    const float* B = (const float*)d_in[2];
    float* out = (float*)d_out;
    router_kernel<<<dim3(NT / TOK), dim3(256), 0, stream>>>(H, W, B, out);
}